// Round 10
// baseline (353.540 us; speedup 1.0000x reference)
//
#include <hip/hip_runtime.h>
#include <hip/hip_bf16.h>
#include <stdint.h>

#define DEV static __device__ __forceinline__

typedef __attribute__((ext_vector_type(8))) short bf16x8;
typedef __attribute__((ext_vector_type(4))) float f32x4;

DEV void async_ld16(const void* g, void* l) {
  __builtin_amdgcn_global_load_lds(
      (const __attribute__((address_space(1))) void*)g,
      (__attribute__((address_space(3))) void*)l, 16, 0, 0);
}

DEV unsigned short f2bf(float f) {
  union { __hip_bfloat16 h; unsigned short u; } c;
  c.h = __float2bfloat16(f);
  return c.u;
}

// ---------------- constants ----------------
#define Bb 16
#define Cc 512
#define Nn 4096   // H*W
#define Kk 32
#define NSPLIT 32 // n-chunks for enc partials (R7-measured best)

// ---------------- K0a: cast conv_w -> bf16 ----------------
__global__ void k_castw(const float* __restrict__ a, __hip_bfloat16* __restrict__ o) {
  int i = blockIdx.x * 256 + threadIdx.x;
  o[i] = __float2bfloat16(a[i]);
}

// ---------------- K0b: codewords -> bf16 + cw_sq ----------------
__global__ void k_cw(const float* __restrict__ cw, __hip_bfloat16* __restrict__ cwb,
                     float* __restrict__ cwsq) {
  int k = blockIdx.x, lane = threadIdx.x; // 64 lanes
  float s = 0.f;
#pragma unroll
  for (int j = 0; j < 8; ++j) {
    float v = cw[k * Cc + lane * 8 + j];
    cwb[k * Cc + lane * 8 + j] = __float2bfloat16(v);
    s += v * v;
  }
  for (int off = 32; off; off >>= 1) s += __shfl_down(s, off);
  if (lane == 0) cwsq[k] = s;
}

// ---------------- K2: z[b,n,c] = x^T . conv_w^T + bias ----------------
// R7 structure (measured best: 94-96us) + 2-DEEP A-register prefetch:
// av0/av1 double reg buffer; A(kt) committed from regs loaded at step kt-2
// (two barriers ago -> L3 latency fully covered); the just-committed reg set
// is immediately reloaded with A(kt+2). B prefetch(t+1)-after-barrier as R7.
__global__ __launch_bounds__(256) void k_gemm_z(const float* __restrict__ X,
                                                const __hip_bfloat16* __restrict__ Bw,
                                                const float* __restrict__ bias,
                                                __hip_bfloat16* __restrict__ Z) {
  constexpr int LDA = 36;                 // padded row stride (shorts)
  constexpr int AE = 128 * LDA;           // shorts per A buffer
  constexpr int BE = 128 * 32;            // bf16 per B buffer
  __shared__ __align__(16) unsigned short As[2 * AE];   // 18432 B
  __shared__ __align__(16) __hip_bfloat16 Bs[2 * BE];   // 16384 B
  const int b = blockIdx.y;
  const int n0 = (blockIdx.x & 31) * 128;
  const int c0 = (blockIdx.x >> 5) * 128;   // c-phase slow: x streams L3 once
  const int tid = threadIdx.x;
  const int lane = tid & 63, wid = tid >> 6;
  const int wr = (wid >> 1) * 64, wc = (wid & 1) * 64;
  const int cg = tid >> 5;   // c-quad 0..7 (2 per wave -> 2x512B coalesced runs)
  const int ng = tid & 31;   // n-quad 0..31
  const float* Xb = X + (size_t)b * Cc * Nn + n0 + ng * 4;
  const __hip_bfloat16* Bbp = Bw + (size_t)c0 * Cc;
  f32x4 acc[4][4] = {};
  float4 av0[4], av1[4];
  // ---- prologue: A(0)->av0, A(1)->av1, B(0)->Bs[0] ----
#pragma unroll
  for (int i = 0; i < 4; ++i)
    av0[i] = *(const float4*)&Xb[(size_t)(cg * 4 + i) * Nn];
#pragma unroll
  for (int i = 0; i < 4; ++i)
    av1[i] = *(const float4*)&Xb[(size_t)(32 + cg * 4 + i) * Nn];
#pragma unroll
  for (int j = 0; j < 2; ++j) {
    int li = tid + j * 256;
    int row = li >> 2;
    int kc = ((li & 3) ^ ((li >> 3) & 3)) * 8;
    async_ld16(Bbp + (size_t)row * Cc + kc, (char*)Bs + li * 16);
  }
  int cur = 0;
  for (int kt = 0; kt < 16; ++kt) {
    // ---- commit A(kt) from the reg set loaded two steps ago ----
    unsigned short* Aw = As + cur * AE;
    int slot = cg ^ (ng & 7);
    const float4* avc = (kt & 1) ? av1 : av0;
#pragma unroll
    for (int j = 0; j < 4; ++j) {
      int n = ng * 4 + j;
      ushort4 w;
      w.x = f2bf(avc[0][j]);
      w.y = f2bf(avc[1][j]);
      w.z = f2bf(avc[2][j]);
      w.w = f2bf(avc[3][j]);
      *(ushort4*)&Aw[n * LDA + slot * 4] = w;
    }
    __syncthreads();  // drains B(kt); A(kt) visible
    // ---- prefetch B(kt+1) into buf^1 (R7-proven) ----
    if (kt < 15) {
      char* Bwr = (char*)(Bs + (cur ^ 1) * BE);
#pragma unroll
      for (int j = 0; j < 2; ++j) {
        int li = tid + j * 256;
        int row = li >> 2;
        int kc = ((li & 3) ^ ((li >> 3) & 3)) * 8;
        async_ld16(Bbp + (size_t)row * Cc + (kt + 1) * 32 + kc, Bwr + li * 16);
      }
    }
    // ---- reload the just-committed reg set with A(kt+2): 2 steps of cover ----
    if (kt < 14) {
      float4* avn = (kt & 1) ? av1 : av0;
#pragma unroll
      for (int i = 0; i < 4; ++i)
        avn[i] = *(const float4*)&Xb[(size_t)((kt + 2) * 32 + cg * 4 + i) * Nn];
    }
    // ---- fragment reads + MFMA ----
    const unsigned short* Ar = As + cur * AE;
    const __hip_bfloat16* Br = Bs + cur * BE;
    bf16x8 af[4], bfv[4];
#pragma unroll
    for (int m = 0; m < 4; ++m) {
      int row = wr + m * 16 + (lane & 15);
      int h = (row >> 2) & 7;
      int g = lane >> 4;
      int s0 = (2 * g) ^ h, s1 = (2 * g + 1) ^ h;
      union { ushort4 u2[2]; bf16x8 v8; } t;
      t.u2[0] = *(const ushort4*)&Ar[row * LDA + s0 * 4];
      t.u2[1] = *(const ushort4*)&Ar[row * LDA + s1 * 4];
      af[m] = t.v8;
    }
#pragma unroll
    for (int nf = 0; nf < 4; ++nf) {
      int row = wc + nf * 16 + (lane & 15);
      int q = (lane >> 4) ^ ((row >> 1) & 3);
      bfv[nf] = *(const bf16x8*)&Br[row * 32 + q * 8];
    }
#pragma unroll
    for (int m = 0; m < 4; ++m)
#pragma unroll
      for (int nf = 0; nf < 4; ++nf)
        acc[m][nf] = __builtin_amdgcn_mfma_f32_16x16x32_bf16(af[m], bfv[nf], acc[m][nf], 0, 0, 0);
    cur ^= 1;
  }
  __hip_bfloat16* Zb = Z + ((size_t)b * Nn + n0) * Cc + c0;
#pragma unroll
  for (int nf = 0; nf < 4; ++nf) {
    int col = wc + nf * 16 + (lane & 15);
    float bv = bias[c0 + col];
#pragma unroll
    for (int m = 0; m < 4; ++m) {
#pragma unroll
      for (int r = 0; r < 4; ++r) {
        int row = wr + m * 16 + (lane >> 4) * 4 + r;
        Zb[(size_t)row * Cc + col] = __float2bfloat16(acc[m][nf][r] + bv);
      }
    }
  }
}

// ---------------- K3: cross + softmax fused -> assign[b,n,k], asum[b,k] ----------------
// R7-measured version: single-buffer, 2 barriers/K-step, swizzled b128 frag reads.
__global__ __launch_bounds__(256) void k_cross(const __hip_bfloat16* __restrict__ Z,
                                               const __hip_bfloat16* __restrict__ CW,
                                               const float* __restrict__ scale,
                                               const float* __restrict__ cwsq,
                                               float* __restrict__ assign,
                                               float* __restrict__ asum) {
  __shared__ __align__(16) __hip_bfloat16 As[128 * 32];
  __shared__ __align__(16) __hip_bfloat16 Bs[32 * 32];
  __shared__ float s_zsq[128];
  __shared__ float s_asum[Kk];
  int b = blockIdx.y;
  int n0 = blockIdx.x * 128;
  int tid = threadIdx.x, lane = tid & 63, wid = tid >> 6;
  if (tid < Kk) s_asum[tid] = 0.f;
  const __hip_bfloat16* Ab = Z + ((size_t)b * Nn + n0) * Cc;
  f32x4 acc[2][2] = {};
  float sq = 0.f;
  for (int kt = 0; kt < 16; ++kt) {
    int k0 = kt * 32;
    __syncthreads();
#pragma unroll
    for (int j = 0; j < 2; ++j) {
      int li = tid + j * 256;
      int row = li >> 2;
      int kc = ((li & 3) ^ ((li >> 3) & 3)) * 8;
      async_ld16(Ab + (size_t)row * Cc + k0 + kc, (char*)As + li * 16);
    }
    if (tid < 128) {
      int row = tid >> 2;
      int kc = ((tid & 3) ^ ((tid >> 3) & 3)) * 8;
      async_ld16(CW + (size_t)row * Cc + k0 + kc, (char*)Bs + tid * 16);
    }
    __syncthreads();
    {  // z_sq partial: 2 swizzled b128 reads
      int row = tid >> 1, h = tid & 1;
      int rsw = (row >> 1) & 3;
#pragma unroll
      for (int c8 = 0; c8 < 2; ++c8) {
        union { bf16x8 v; __hip_bfloat16 e[8]; } t;
        t.v = *(const bf16x8*)&As[row * 32 + (((2 * h + c8) ^ rsw) * 8)];
#pragma unroll
        for (int i = 0; i < 8; ++i) {
          float v = __bfloat162float(t.e[i]);
          sq += v * v;
        }
      }
    }
    bf16x8 af[2], bfv[2];
#pragma unroll
    for (int m = 0; m < 2; ++m) {
      int row = wid * 32 + m * 16 + (lane & 15);
      int q = (lane >> 4) ^ ((row >> 1) & 3);
      af[m] = *(const bf16x8*)&As[row * 32 + q * 8];
    }
#pragma unroll
    for (int nf = 0; nf < 2; ++nf) {
      int row = nf * 16 + (lane & 15);
      int q = (lane >> 4) ^ ((row >> 1) & 3);
      bfv[nf] = *(const bf16x8*)&Bs[row * 32 + q * 8];
    }
#pragma unroll
    for (int m = 0; m < 2; ++m)
#pragma unroll
      for (int nf = 0; nf < 2; ++nf)
        acc[m][nf] = __builtin_amdgcn_mfma_f32_16x16x32_bf16(af[m], bfv[nf], acc[m][nf], 0, 0, 0);
  }
  sq += __shfl_xor(sq, 1);
  if ((tid & 1) == 0) s_zsq[tid >> 1] = sq;
  __syncthreads();
  // ---- in-register softmax over k ----
  float sc[2], cq[2];
#pragma unroll
  for (int nf = 0; nf < 2; ++nf) {
    sc[nf] = scale[nf * 16 + (lane & 15)];
    cq[nf] = cwsq[nf * 16 + (lane & 15)];
  }
  float asump0 = 0.f, asump1 = 0.f;
#pragma unroll
  for (int m = 0; m < 2; ++m) {
#pragma unroll
    for (int r = 0; r < 4; ++r) {
      int row = wid * 32 + m * 16 + (lane >> 4) * 4 + r;
      float zq = s_zsq[row];
      float v0 = sc[0] * (zq - 2.f * acc[m][0][r] + cq[0]);
      float v1 = sc[1] * (zq - 2.f * acc[m][1][r] + cq[1]);
      float mx = fmaxf(v0, v1);
#pragma unroll
      for (int off = 1; off < 16; off <<= 1) mx = fmaxf(mx, __shfl_xor(mx, off));
      float e0 = __expf(v0 - mx), e1 = __expf(v1 - mx);
      float s = e0 + e1;
#pragma unroll
      for (int off = 1; off < 16; off <<= 1) s += __shfl_xor(s, off);
      float inv = 1.f / s;
      float a0 = e0 * inv, a1 = e1 * inv;
      acc[m][0][r] = a0;
      acc[m][1][r] = a1;
      asump0 += a0;
      asump1 += a1;
    }
  }
  asump0 += __shfl_xor(asump0, 16); asump0 += __shfl_xor(asump0, 32);
  asump1 += __shfl_xor(asump1, 16); asump1 += __shfl_xor(asump1, 32);
  if (lane < 16) {
    atomicAdd(&s_asum[lane], asump0);
    atomicAdd(&s_asum[16 + lane], asump1);
  }
  float* Cb = assign + ((size_t)b * Nn + n0) * Kk;
#pragma unroll
  for (int m = 0; m < 2; ++m)
#pragma unroll
    for (int nf = 0; nf < 2; ++nf) {
      int col = nf * 16 + (lane & 15);
#pragma unroll
      for (int r = 0; r < 4; ++r) {
        int row = wid * 32 + m * 16 + (lane >> 4) * 4 + r;
        Cb[(size_t)row * Kk + col] = acc[m][nf][r];
      }
    }
  __syncthreads();
  if (tid < Kk) atomicAdd(&asum[b * Kk + tid], s_asum[tid]);
}

// ---------------- K5: enc partials: part[s][b][k][c]  (128-n chunks, R7 best) ----------------
__global__ __launch_bounds__(256) void k_enc_part(const float* __restrict__ assign,
                                                  const __hip_bfloat16* __restrict__ Z,
                                                  float* __restrict__ part) {
  __shared__ float sa[128][Kk];
  int b = blockIdx.z;
  int s = blockIdx.y;
  int c = blockIdx.x * 256 + threadIdx.x;
  int tid = threadIdx.x;
  int n0 = s * 128;
  const float* ap = assign + ((size_t)b * Nn + n0) * Kk;
  for (int i = tid; i < 128 * Kk; i += 256) sa[i >> 5][i & 31] = ap[i];
  __syncthreads();
  float acc[Kk];
#pragma unroll
  for (int k = 0; k < Kk; ++k) acc[k] = 0.f;
  const __hip_bfloat16* zp = Z + ((size_t)b * Nn + n0) * Cc + c;
  for (int n = 0; n < 128; ++n) {
    float zv = __bfloat162float(zp[(size_t)n * Cc]);
    const float4* sp = (const float4*)&sa[n][0];
#pragma unroll
    for (int q = 0; q < 8; ++q) {
      float4 a4 = sp[q];
      acc[4 * q + 0] = fmaf(a4.x, zv, acc[4 * q + 0]);
      acc[4 * q + 1] = fmaf(a4.y, zv, acc[4 * q + 1]);
      acc[4 * q + 2] = fmaf(a4.z, zv, acc[4 * q + 2]);
      acc[4 * q + 3] = fmaf(a4.w, zv, acc[4 * q + 3]);
    }
  }
  float* pp = part + (((size_t)s * Bb + b) * Kk) * Cc + c;
#pragma unroll
  for (int k = 0; k < Kk; ++k) pp[(size_t)k * Cc] = acc[k];
}

// ---------------- K6: reduce partials + BN + relu + mean-atomic -> ef ----------------
__global__ __launch_bounds__(256) void k_enc_bn(const float* __restrict__ part,
                                                const float* __restrict__ asum,
                                                const float* __restrict__ cw,
                                                const float* __restrict__ bn_g,
                                                const float* __restrict__ bn_b,
                                                const float* __restrict__ bn_m,
                                                const float* __restrict__ bn_v,
                                                float* __restrict__ ef) {
  int bk = blockIdx.x;  // b*32+k
  int b = bk >> 5, k = bk & 31;
  int tid = threadIdx.x;
  float g = bn_g[k], bt = bn_b[k], mn = bn_m[k], iv = rsqrtf(bn_v[k] + 1e-5f);
  float as = asum[bk];
  for (int c = tid; c < Cc; c += 256) {
    float e = 0.f;
#pragma unroll
    for (int s = 0; s < NSPLIT; ++s)
      e += part[(((size_t)s * Bb + b) * Kk + k) * Cc + c];
    e -= as * cw[k * Cc + c];
    e = (e - mn) * (iv * g) + bt;
    e = fmaxf(e, 0.f);
    atomicAdd(&ef[b * Cc + c], e * (1.f / 32.f));
  }
}

// ---------------- K8: fc + sigmoid -> gamma[b][o] ----------------
__global__ void k_fc(const float* __restrict__ ef, const float* __restrict__ fcw,
                     const float* __restrict__ fcb, float* __restrict__ gamma) {
  int b = blockIdx.x;
  int o = blockIdx.y * 4 + (threadIdx.x >> 6);
  int lane = threadIdx.x & 63;
  const float* w = fcw + (size_t)o * Cc;
  const float* e = ef + b * Cc;
  float s = 0.f;
#pragma unroll
  for (int j = 0; j < 8; ++j) s += e[lane + j * 64] * w[lane + j * 64];
  for (int off = 32; off; off >>= 1) s += __shfl_down(s, off);
  if (lane == 0) gamma[b * Cc + o] = 1.f / (1.f + __expf(-(s + fcb[o])));
}

// ---------------- K9: output = relu(x * (1+gamma)), one block per (b,c) ----------------
__global__ __launch_bounds__(256) void k_out(const float* __restrict__ x,
                                             const float* __restrict__ gamma,
                                             float* __restrict__ out) {
  int bc = blockIdx.x;
  float m = 1.f + gamma[bc];
  size_t base = (size_t)bc * (Nn / 4);
  const float4* xp = (const float4*)x + base;
  float4* op = (float4*)out + base;
#pragma unroll
  for (int j = 0; j < 4; ++j) {
    int i = j * 256 + threadIdx.x;
    float4 v = xp[i];
    float4 r;
    r.x = fmaxf(v.x * m, 0.f);
    r.y = fmaxf(v.y * m, 0.f);
    r.z = fmaxf(v.z * m, 0.f);
    r.w = fmaxf(v.w * m, 0.f);
    op[i] = r;
  }
}

extern "C" void kernel_launch(void* const* d_in, const int* in_sizes, int n_in,
                              void* d_out, int out_size, void* d_ws, size_t ws_size,
                              hipStream_t stream) {
  const float* x = (const float*)d_in[0];
  const float* conv_w = (const float*)d_in[1];
  const float* conv_b = (const float*)d_in[2];
  const float* codewords = (const float*)d_in[3];
  const float* scale = (const float*)d_in[4];
  const float* bn_gamma = (const float*)d_in[5];
  const float* bn_beta = (const float*)d_in[6];
  const float* bn_mean = (const float*)d_in[7];
  const float* bn_var = (const float*)d_in[8];
  const float* fc_w = (const float*)d_in[9];
  const float* fc_b = (const float*)d_in[10];

  float* ef_out = (float*)d_out;            // [16][512]
  float* out = (float*)d_out + Bb * Cc;     // [16][512][4096]

  char* ws = (char*)d_ws;
  size_t off = 0;
  float* part = (float*)(ws + off);                  // 32 MB
  off += (size_t)NSPLIT * Bb * Kk * Cc * 4;
  __hip_bfloat16* z = (__hip_bfloat16*)(ws + off);   // 64 MB
  off += (size_t)Bb * Nn * Cc * 2;
  float* assign = (float*)(ws + off);                // 8 MB
  off += (size_t)Bb * Nn * Kk * 4;
  __hip_bfloat16* wbf = (__hip_bfloat16*)(ws + off);
  off += (size_t)Cc * Cc * 2;
  __hip_bfloat16* cwb = (__hip_bfloat16*)(ws + off);
  off += (size_t)Kk * Cc * 2;
  float* cwsq = (float*)(ws + off);
  off += 512;
  float* asum = (float*)(ws + off);
  off += (size_t)Bb * Kk * 4;
  float* gamma = (float*)(ws + off);
  off += (size_t)Bb * Cc * 4;
  (void)ws_size; (void)n_in; (void)in_sizes; (void)out_size;

  hipMemsetAsync(asum, 0, Bb * Kk * 4, stream);
  hipMemsetAsync(ef_out, 0, Bb * Cc * 4, stream);  // mean accumulated via atomics

  k_castw<<<dim3(Cc * Cc / 256), dim3(256), 0, stream>>>(conv_w, wbf);
  k_cw<<<dim3(Kk), dim3(64), 0, stream>>>(codewords, cwb, cwsq);
  k_gemm_z<<<dim3((Nn / 128) * 4, Bb), dim3(256), 0, stream>>>(x, wbf, conv_b, z);
  k_cross<<<dim3(Nn / 128, Bb), dim3(256), 0, stream>>>(z, cwb, scale, cwsq, assign, asum);
  k_enc_part<<<dim3(Cc / 256, NSPLIT, Bb), dim3(256), 0, stream>>>(assign, z, part);
  k_enc_bn<<<dim3(Bb * Kk), dim3(256), 0, stream>>>(part, asum, codewords, bn_gamma, bn_beta,
                                                    bn_mean, bn_var, ef_out);
  k_fc<<<dim3(Bb, Cc / 4), dim3(256), 0, stream>>>(ef_out, fc_w, fc_b, gamma);
  k_out<<<dim3(Bb * Cc), dim3(256), 0, stream>>>(x, gamma, out);
}

// Round 11
// 190.778 us; speedup vs baseline: 1.8531x; 1.8531x over previous
//
#include <hip/hip_runtime.h>
#include <hip/hip_bf16.h>
#include <stdint.h>

#define DEV static __device__ __forceinline__

typedef __attribute__((ext_vector_type(8))) short bf16x8;
typedef __attribute__((ext_vector_type(4))) float f32x4;

DEV void async_ld16(const void* g, void* l) {
  __builtin_amdgcn_global_load_lds(
      (const __attribute__((address_space(1))) void*)g,
      (__attribute__((address_space(3))) void*)l, 16, 0, 0);
}

DEV unsigned short f2bf(float f) {
  union { __hip_bfloat16 h; unsigned short u; } c;
  c.h = __float2bfloat16(f);
  return c.u;
}

// ---------------- constants ----------------
#define Bb 16
#define Cc 512
#define Nn 4096   // H*W
#define Kk 32
#define NSPLIT 32 // n-chunks for enc partials (R7-measured best)

// ---------------- K0a: cast conv_w -> bf16 ----------------
__global__ void k_castw(const float* __restrict__ a, __hip_bfloat16* __restrict__ o) {
  int i = blockIdx.x * 256 + threadIdx.x;
  o[i] = __float2bfloat16(a[i]);
}

// ---------------- K0b: codewords -> bf16 + cw_sq ----------------
__global__ void k_cw(const float* __restrict__ cw, __hip_bfloat16* __restrict__ cwb,
                     float* __restrict__ cwsq) {
  int k = blockIdx.x, lane = threadIdx.x; // 64 lanes
  float s = 0.f;
#pragma unroll
  for (int j = 0; j < 8; ++j) {
    float v = cw[k * Cc + lane * 8 + j];
    cwb[k * Cc + lane * 8 + j] = __float2bfloat16(v);
    s += v * v;
  }
  for (int off = 32; off; off >>= 1) s += __shfl_down(s, off);
  if (lane == 0) cwsq[k] = s;
}

// ---------------- K2: z[b,n,c] = x^T . conv_w^T + bias ----------------
// R7 structure (measured best) + 2-deep A-reg prefetch via STATIC unroll-by-2:
// av0/av1 referenced by NAME in two macro-expanded step bodies (rule #20 safe,
// no scratch). Commit(kt) uses regs loaded at kt-2 (drained a barrier ago) ->
// ds_write never vmcnt-stalls. A(kt+2) issues after barrier(kt), drains at
// barrier(kt+1) together with B(kt+1). B path identical to R7.
__global__ __launch_bounds__(256) void k_gemm_z(const float* __restrict__ X,
                                                const __hip_bfloat16* __restrict__ Bw,
                                                const float* __restrict__ bias,
                                                __hip_bfloat16* __restrict__ Z) {
  constexpr int LDA = 36;                 // padded row stride (shorts)
  constexpr int AE = 128 * LDA;           // shorts per A buffer
  constexpr int BE = 128 * 32;            // bf16 per B buffer
  __shared__ __align__(16) unsigned short As[2 * AE];   // 18432 B
  __shared__ __align__(16) __hip_bfloat16 Bs[2 * BE];   // 16384 B
  const int b = blockIdx.y;
  const int n0 = (blockIdx.x & 31) * 128;
  const int c0 = (blockIdx.x >> 5) * 128;   // c-phase slow: x streams L3 once
  const int tid = threadIdx.x;
  const int lane = tid & 63, wid = tid >> 6;
  const int wr = (wid >> 1) * 64, wc = (wid & 1) * 64;
  const int cg = tid >> 5;   // c-quad 0..7 (2 per wave -> 2x512B coalesced runs)
  const int ng = tid & 31;   // n-quad 0..31
  const int slot = cg ^ (ng & 7);
  const float* Xb = X + (size_t)b * Cc * Nn + n0 + ng * 4;
  const __hip_bfloat16* Bbp = Bw + (size_t)c0 * Cc;
  f32x4 acc[4][4] = {};
  float4 av0[4], av1[4];
  // ---- prologue: A(0)->av0, A(1)->av1, B(0)->Bs[0] ----
#pragma unroll
  for (int i = 0; i < 4; ++i)
    av0[i] = *(const float4*)&Xb[(size_t)(cg * 4 + i) * Nn];
#pragma unroll
  for (int i = 0; i < 4; ++i)
    av1[i] = *(const float4*)&Xb[(size_t)(32 + cg * 4 + i) * Nn];
#pragma unroll
  for (int j = 0; j < 2; ++j) {
    int li = tid + j * 256;
    int row = li >> 2;
    int kc = ((li & 3) ^ ((li >> 3) & 3)) * 8;
    async_ld16(Bbp + (size_t)row * Cc + kc, (char*)Bs + li * 16);
  }
  int cur = 0;

#define GEMM_STEP(KT, AV)                                                      \
  {                                                                            \
    unsigned short* Aw = As + cur * AE;                                        \
    _Pragma("unroll")                                                          \
    for (int j = 0; j < 4; ++j) {                                              \
      int n = ng * 4 + j;                                                      \
      ushort4 w;                                                               \
      w.x = f2bf(AV[0][j]);                                                    \
      w.y = f2bf(AV[1][j]);                                                    \
      w.z = f2bf(AV[2][j]);                                                    \
      w.w = f2bf(AV[3][j]);                                                    \
      *(ushort4*)&Aw[n * LDA + slot * 4] = w;                                  \
    }                                                                          \
    __syncthreads();                                                           \
    if ((KT) < 15) {                                                           \
      char* Bwr = (char*)(Bs + (cur ^ 1) * BE);                                \
      _Pragma("unroll")                                                        \
      for (int j = 0; j < 2; ++j) {                                            \
        int li = tid + j * 256;                                                \
        int row = li >> 2;                                                     \
        int kc = ((li & 3) ^ ((li >> 3) & 3)) * 8;                             \
        async_ld16(Bbp + (size_t)row * Cc + ((KT) + 1) * 32 + kc,              \
                   Bwr + li * 16);                                             \
      }                                                                        \
    }                                                                          \
    if ((KT) < 14) {                                                           \
      _Pragma("unroll")                                                        \
      for (int i = 0; i < 4; ++i)                                              \
        AV[i] = *(const float4*)&Xb[(size_t)(((KT) + 2) * 32 + cg * 4 + i) *   \
                                    Nn];                                       \
    }                                                                          \
    const unsigned short* Ar = As + cur * AE;                                  \
    const __hip_bfloat16* Br = Bs + cur * BE;                                  \
    bf16x8 af[4], bfv[4];                                                      \
    _Pragma("unroll")                                                          \
    for (int m = 0; m < 4; ++m) {                                              \
      int row = wr + m * 16 + (lane & 15);                                     \
      int h = (row >> 2) & 7;                                                  \
      int g = lane >> 4;                                                       \
      int s0 = (2 * g) ^ h, s1 = (2 * g + 1) ^ h;                              \
      union { ushort4 u2[2]; bf16x8 v8; } t;                                   \
      t.u2[0] = *(const ushort4*)&Ar[row * LDA + s0 * 4];                      \
      t.u2[1] = *(const ushort4*)&Ar[row * LDA + s1 * 4];                      \
      af[m] = t.v8;                                                            \
    }                                                                          \
    _Pragma("unroll")                                                          \
    for (int nf = 0; nf < 4; ++nf) {                                           \
      int row = wc + nf * 16 + (lane & 15);                                    \
      int q = (lane >> 4) ^ ((row >> 1) & 3);                                  \
      bfv[nf] = *(const bf16x8*)&Br[row * 32 + q * 8];                         \
    }                                                                          \
    _Pragma("unroll")                                                          \
    for (int m = 0; m < 4; ++m)                                                \
      _Pragma("unroll")                                                        \
      for (int nf = 0; nf < 4; ++nf)                                           \
        acc[m][nf] =                                                           \
            __builtin_amdgcn_mfma_f32_16x16x32_bf16(af[m], bfv[nf],            \
                                                    acc[m][nf], 0, 0, 0);      \
    cur ^= 1;                                                                  \
  }

  for (int kt = 0; kt < 16; kt += 2) {
    GEMM_STEP(kt, av0)
    GEMM_STEP(kt + 1, av1)
  }
#undef GEMM_STEP

  __hip_bfloat16* Zb = Z + ((size_t)b * Nn + n0) * Cc + c0;
#pragma unroll
  for (int nf = 0; nf < 4; ++nf) {
    int col = wc + nf * 16 + (lane & 15);
    float bv = bias[c0 + col];
#pragma unroll
    for (int m = 0; m < 4; ++m) {
#pragma unroll
      for (int r = 0; r < 4; ++r) {
        int row = wr + m * 16 + (lane >> 4) * 4 + r;
        Zb[(size_t)row * Cc + col] = __float2bfloat16(acc[m][nf][r] + bv);
      }
    }
  }
}

// ---------------- K3: cross + softmax fused -> assign[b,n,k], asum[b,k] ----------------
// R7-measured version: single-buffer, 2 barriers/K-step, swizzled b128 frag reads.
__global__ __launch_bounds__(256) void k_cross(const __hip_bfloat16* __restrict__ Z,
                                               const __hip_bfloat16* __restrict__ CW,
                                               const float* __restrict__ scale,
                                               const float* __restrict__ cwsq,
                                               float* __restrict__ assign,
                                               float* __restrict__ asum) {
  __shared__ __align__(16) __hip_bfloat16 As[128 * 32];
  __shared__ __align__(16) __hip_bfloat16 Bs[32 * 32];
  __shared__ float s_zsq[128];
  __shared__ float s_asum[Kk];
  int b = blockIdx.y;
  int n0 = blockIdx.x * 128;
  int tid = threadIdx.x, lane = tid & 63, wid = tid >> 6;
  if (tid < Kk) s_asum[tid] = 0.f;
  const __hip_bfloat16* Ab = Z + ((size_t)b * Nn + n0) * Cc;
  f32x4 acc[2][2] = {};
  float sq = 0.f;
  for (int kt = 0; kt < 16; ++kt) {
    int k0 = kt * 32;
    __syncthreads();
#pragma unroll
    for (int j = 0; j < 2; ++j) {
      int li = tid + j * 256;
      int row = li >> 2;
      int kc = ((li & 3) ^ ((li >> 3) & 3)) * 8;
      async_ld16(Ab + (size_t)row * Cc + k0 + kc, (char*)As + li * 16);
    }
    if (tid < 128) {
      int row = tid >> 2;
      int kc = ((tid & 3) ^ ((tid >> 3) & 3)) * 8;
      async_ld16(CW + (size_t)row * Cc + k0 + kc, (char*)Bs + tid * 16);
    }
    __syncthreads();
    {  // z_sq partial: 2 swizzled b128 reads
      int row = tid >> 1, h = tid & 1;
      int rsw = (row >> 1) & 3;
#pragma unroll
      for (int c8 = 0; c8 < 2; ++c8) {
        union { bf16x8 v; __hip_bfloat16 e[8]; } t;
        t.v = *(const bf16x8*)&As[row * 32 + (((2 * h + c8) ^ rsw) * 8)];
#pragma unroll
        for (int i = 0; i < 8; ++i) {
          float v = __bfloat162float(t.e[i]);
          sq += v * v;
        }
      }
    }
    bf16x8 af[2], bfv[2];
#pragma unroll
    for (int m = 0; m < 2; ++m) {
      int row = wid * 32 + m * 16 + (lane & 15);
      int q = (lane >> 4) ^ ((row >> 1) & 3);
      af[m] = *(const bf16x8*)&As[row * 32 + q * 8];
    }
#pragma unroll
    for (int nf = 0; nf < 2; ++nf) {
      int row = nf * 16 + (lane & 15);
      int q = (lane >> 4) ^ ((row >> 1) & 3);
      bfv[nf] = *(const bf16x8*)&Bs[row * 32 + q * 8];
    }
#pragma unroll
    for (int m = 0; m < 2; ++m)
#pragma unroll
      for (int nf = 0; nf < 2; ++nf)
        acc[m][nf] = __builtin_amdgcn_mfma_f32_16x16x32_bf16(af[m], bfv[nf], acc[m][nf], 0, 0, 0);
  }
  sq += __shfl_xor(sq, 1);
  if ((tid & 1) == 0) s_zsq[tid >> 1] = sq;
  __syncthreads();
  // ---- in-register softmax over k ----
  float sc[2], cq[2];
#pragma unroll
  for (int nf = 0; nf < 2; ++nf) {
    sc[nf] = scale[nf * 16 + (lane & 15)];
    cq[nf] = cwsq[nf * 16 + (lane & 15)];
  }
  float asump0 = 0.f, asump1 = 0.f;
#pragma unroll
  for (int m = 0; m < 2; ++m) {
#pragma unroll
    for (int r = 0; r < 4; ++r) {
      int row = wid * 32 + m * 16 + (lane >> 4) * 4 + r;
      float zq = s_zsq[row];
      float v0 = sc[0] * (zq - 2.f * acc[m][0][r] + cq[0]);
      float v1 = sc[1] * (zq - 2.f * acc[m][1][r] + cq[1]);
      float mx = fmaxf(v0, v1);
#pragma unroll
      for (int off = 1; off < 16; off <<= 1) mx = fmaxf(mx, __shfl_xor(mx, off));
      float e0 = __expf(v0 - mx), e1 = __expf(v1 - mx);
      float s = e0 + e1;
#pragma unroll
      for (int off = 1; off < 16; off <<= 1) s += __shfl_xor(s, off);
      float inv = 1.f / s;
      float a0 = e0 * inv, a1 = e1 * inv;
      acc[m][0][r] = a0;
      acc[m][1][r] = a1;
      asump0 += a0;
      asump1 += a1;
    }
  }
  asump0 += __shfl_xor(asump0, 16); asump0 += __shfl_xor(asump0, 32);
  asump1 += __shfl_xor(asump1, 16); asump1 += __shfl_xor(asump1, 32);
  if (lane < 16) {
    atomicAdd(&s_asum[lane], asump0);
    atomicAdd(&s_asum[16 + lane], asump1);
  }
  float* Cb = assign + ((size_t)b * Nn + n0) * Kk;
#pragma unroll
  for (int m = 0; m < 2; ++m)
#pragma unroll
    for (int nf = 0; nf < 2; ++nf) {
      int col = nf * 16 + (lane & 15);
#pragma unroll
      for (int r = 0; r < 4; ++r) {
        int row = wid * 32 + m * 16 + (lane >> 4) * 4 + r;
        Cb[(size_t)row * Kk + col] = acc[m][nf][r];
      }
    }
  __syncthreads();
  if (tid < Kk) atomicAdd(&asum[b * Kk + tid], s_asum[tid]);
}

// ---------------- K5: enc partials: part[s][b][k][c]  (128-n chunks, R7 best) ----------------
__global__ __launch_bounds__(256) void k_enc_part(const float* __restrict__ assign,
                                                  const __hip_bfloat16* __restrict__ Z,
                                                  float* __restrict__ part) {
  __shared__ float sa[128][Kk];
  int b = blockIdx.z;
  int s = blockIdx.y;
  int c = blockIdx.x * 256 + threadIdx.x;
  int tid = threadIdx.x;
  int n0 = s * 128;
  const float* ap = assign + ((size_t)b * Nn + n0) * Kk;
  for (int i = tid; i < 128 * Kk; i += 256) sa[i >> 5][i & 31] = ap[i];
  __syncthreads();
  float acc[Kk];
#pragma unroll
  for (int k = 0; k < Kk; ++k) acc[k] = 0.f;
  const __hip_bfloat16* zp = Z + ((size_t)b * Nn + n0) * Cc + c;
  for (int n = 0; n < 128; ++n) {
    float zv = __bfloat162float(zp[(size_t)n * Cc]);
    const float4* sp = (const float4*)&sa[n][0];
#pragma unroll
    for (int q = 0; q < 8; ++q) {
      float4 a4 = sp[q];
      acc[4 * q + 0] = fmaf(a4.x, zv, acc[4 * q + 0]);
      acc[4 * q + 1] = fmaf(a4.y, zv, acc[4 * q + 1]);
      acc[4 * q + 2] = fmaf(a4.z, zv, acc[4 * q + 2]);
      acc[4 * q + 3] = fmaf(a4.w, zv, acc[4 * q + 3]);
    }
  }
  float* pp = part + (((size_t)s * Bb + b) * Kk) * Cc + c;
#pragma unroll
  for (int k = 0; k < Kk; ++k) pp[(size_t)k * Cc] = acc[k];
}

// ---------------- K6: reduce partials + BN + relu + mean-atomic -> ef ----------------
__global__ __launch_bounds__(256) void k_enc_bn(const float* __restrict__ part,
                                                const float* __restrict__ asum,
                                                const float* __restrict__ cw,
                                                const float* __restrict__ bn_g,
                                                const float* __restrict__ bn_b,
                                                const float* __restrict__ bn_m,
                                                const float* __restrict__ bn_v,
                                                float* __restrict__ ef) {
  int bk = blockIdx.x;  // b*32+k
  int b = bk >> 5, k = bk & 31;
  int tid = threadIdx.x;
  float g = bn_g[k], bt = bn_b[k], mn = bn_m[k], iv = rsqrtf(bn_v[k] + 1e-5f);
  float as = asum[bk];
  for (int c = tid; c < Cc; c += 256) {
    float e = 0.f;
#pragma unroll
    for (int s = 0; s < NSPLIT; ++s)
      e += part[(((size_t)s * Bb + b) * Kk + k) * Cc + c];
    e -= as * cw[k * Cc + c];
    e = (e - mn) * (iv * g) + bt;
    e = fmaxf(e, 0.f);
    atomicAdd(&ef[b * Cc + c], e * (1.f / 32.f));
  }
}

// ---------------- K8: fc + sigmoid -> gamma[b][o] ----------------
__global__ void k_fc(const float* __restrict__ ef, const float* __restrict__ fcw,
                     const float* __restrict__ fcb, float* __restrict__ gamma) {
  int b = blockIdx.x;
  int o = blockIdx.y * 4 + (threadIdx.x >> 6);
  int lane = threadIdx.x & 63;
  const float* w = fcw + (size_t)o * Cc;
  const float* e = ef + b * Cc;
  float s = 0.f;
#pragma unroll
  for (int j = 0; j < 8; ++j) s += e[lane + j * 64] * w[lane + j * 64];
  for (int off = 32; off; off >>= 1) s += __shfl_down(s, off);
  if (lane == 0) gamma[b * Cc + o] = 1.f / (1.f + __expf(-(s + fcb[o])));
}

// ---------------- K9: output = relu(x * (1+gamma)), one block per (b,c) ----------------
__global__ __launch_bounds__(256) void k_out(const float* __restrict__ x,
                                             const float* __restrict__ gamma,
                                             float* __restrict__ out) {
  int bc = blockIdx.x;
  float m = 1.f + gamma[bc];
  size_t base = (size_t)bc * (Nn / 4);
  const float4* xp = (const float4*)x + base;
  float4* op = (float4*)out + base;
#pragma unroll
  for (int j = 0; j < 4; ++j) {
    int i = j * 256 + threadIdx.x;
    float4 v = xp[i];
    float4 r;
    r.x = fmaxf(v.x * m, 0.f);
    r.y = fmaxf(v.y * m, 0.f);
    r.z = fmaxf(v.z * m, 0.f);
    r.w = fmaxf(v.w * m, 0.f);
    op[i] = r;
  }
}

extern "C" void kernel_launch(void* const* d_in, const int* in_sizes, int n_in,
                              void* d_out, int out_size, void* d_ws, size_t ws_size,
                              hipStream_t stream) {
  const float* x = (const float*)d_in[0];
  const float* conv_w = (const float*)d_in[1];
  const float* conv_b = (const float*)d_in[2];
  const float* codewords = (const float*)d_in[3];
  const float* scale = (const float*)d_in[4];
  const float* bn_gamma = (const float*)d_in[5];
  const float* bn_beta = (const float*)d_in[6];
  const float* bn_mean = (const float*)d_in[7];
  const float* bn_var = (const float*)d_in[8];
  const float* fc_w = (const float*)d_in[9];
  const float* fc_b = (const float*)d_in[10];

  float* ef_out = (float*)d_out;            // [16][512]
  float* out = (float*)d_out + Bb * Cc;     // [16][512][4096]

  char* ws = (char*)d_ws;
  size_t off = 0;
  float* part = (float*)(ws + off);                  // 32 MB
  off += (size_t)NSPLIT * Bb * Kk * Cc * 4;
  __hip_bfloat16* z = (__hip_bfloat16*)(ws + off);   // 64 MB
  off += (size_t)Bb * Nn * Cc * 2;
  float* assign = (float*)(ws + off);                // 8 MB
  off += (size_t)Bb * Nn * Kk * 4;
  __hip_bfloat16* wbf = (__hip_bfloat16*)(ws + off);
  off += (size_t)Cc * Cc * 2;
  __hip_bfloat16* cwb = (__hip_bfloat16*)(ws + off);
  off += (size_t)Kk * Cc * 2;
  float* cwsq = (float*)(ws + off);
  off += 512;
  float* asum = (float*)(ws + off);
  off += (size_t)Bb * Kk * 4;
  float* gamma = (float*)(ws + off);
  off += (size_t)Bb * Cc * 4;
  (void)ws_size; (void)n_in; (void)in_sizes; (void)out_size;

  hipMemsetAsync(asum, 0, Bb * Kk * 4, stream);
  hipMemsetAsync(ef_out, 0, Bb * Cc * 4, stream);  // mean accumulated via atomics

  k_castw<<<dim3(Cc * Cc / 256), dim3(256), 0, stream>>>(conv_w, wbf);
  k_cw<<<dim3(Kk), dim3(64), 0, stream>>>(codewords, cwb, cwsq);
  k_gemm_z<<<dim3((Nn / 128) * 4, Bb), dim3(256), 0, stream>>>(x, wbf, conv_b, z);
  k_cross<<<dim3(Nn / 128, Bb), dim3(256), 0, stream>>>(z, cwb, scale, cwsq, assign, asum);
  k_enc_part<<<dim3(Cc / 256, NSPLIT, Bb), dim3(256), 0, stream>>>(assign, z, part);
  k_enc_bn<<<dim3(Bb * Kk), dim3(256), 0, stream>>>(part, asum, codewords, bn_gamma, bn_beta,
                                                    bn_mean, bn_var, ef_out);
  k_fc<<<dim3(Bb, Cc / 4), dim3(256), 0, stream>>>(ef_out, fc_w, fc_b, gamma);
  k_out<<<dim3(Bb * Cc), dim3(256), 0, stream>>>(x, gamma, out);
}

// Round 12
// 186.108 us; speedup vs baseline: 1.8997x; 1.0251x over previous
//
#include <hip/hip_runtime.h>
#include <hip/hip_bf16.h>
#include <stdint.h>

#define DEV static __device__ __forceinline__

typedef __attribute__((ext_vector_type(8))) short bf16x8;
typedef __attribute__((ext_vector_type(4))) float f32x4;

DEV void async_ld16(const void* g, void* l) {
  __builtin_amdgcn_global_load_lds(
      (const __attribute__((address_space(1))) void*)g,
      (__attribute__((address_space(3))) void*)l, 16, 0, 0);
}

DEV unsigned short f2bf(float f) {
  union { __hip_bfloat16 h; unsigned short u; } c;
  c.h = __float2bfloat16(f);
  return c.u;
}

// ---------------- constants ----------------
#define Bb 16
#define Cc 512
#define Nn 4096   // H*W
#define Kk 32
#define NSPLIT 32 // n-chunks for enc partials (R7-measured best)

// ---------------- K0: conv_w cast + codewords cast + cw_sq (merged) ----------------
__global__ void k_prep(const float* __restrict__ conv_w, __hip_bfloat16* __restrict__ wbf,
                       const float* __restrict__ cw, __hip_bfloat16* __restrict__ cwb,
                       float* __restrict__ cwsq) {
  int bid = blockIdx.x;
  if (bid < 1024) {
    int i = bid * 256 + threadIdx.x;
    wbf[i] = __float2bfloat16(conv_w[i]);
  } else {
    int k = (bid - 1024) * 4 + (threadIdx.x >> 6);
    int lane = threadIdx.x & 63;
    float s = 0.f;
#pragma unroll
    for (int j = 0; j < 8; ++j) {
      float v = cw[k * Cc + lane * 8 + j];
      cwb[k * Cc + lane * 8 + j] = __float2bfloat16(v);
      s += v * v;
    }
    for (int off = 32; off; off >>= 1) s += __shfl_down(s, off);
    if (lane == 0) cwsq[k] = s;
  }
}

// ---------------- K2: z[b,n,c] = x^T . conv_w^T + bias (R7-exact, measured best) ----------------
// 256 threads, BM=BN=128, dbuf, 1 barrier/K-step.
//  (a) A-write slot-XOR slot=cg^(ng&7) on pad-36 rows; frag reads paired b64
//  (b) B via global_load_lds, global-source chunk pre-XOR (involution) + swizzled b128 reads
//  (c) B(t+1) issued right AFTER the barrier into buf^1; A(t+1) regs after barrier
__global__ __launch_bounds__(256) void k_gemm_z(const float* __restrict__ X,
                                                const __hip_bfloat16* __restrict__ Bw,
                                                const float* __restrict__ bias,
                                                __hip_bfloat16* __restrict__ Z) {
  constexpr int LDA = 36;                 // padded row stride (shorts)
  constexpr int AE = 128 * LDA;           // shorts per A buffer
  constexpr int BE = 128 * 32;            // bf16 per B buffer
  __shared__ __align__(16) unsigned short As[2 * AE];   // 18432 B
  __shared__ __align__(16) __hip_bfloat16 Bs[2 * BE];   // 16384 B
  const int b = blockIdx.y;
  const int n0 = (blockIdx.x & 31) * 128;
  const int c0 = (blockIdx.x >> 5) * 128;   // c-phase slow: x streams L3 once
  const int tid = threadIdx.x;
  const int lane = tid & 63, wid = tid >> 6;
  const int wr = (wid >> 1) * 64, wc = (wid & 1) * 64;
  const int cg = tid >> 5;   // c-quad 0..7 (2 per wave -> 2x512B coalesced runs)
  const int ng = tid & 31;   // n-quad 0..31
  const float* Xb = X + (size_t)b * Cc * Nn + n0 + ng * 4;
  const __hip_bfloat16* Bbp = Bw + (size_t)c0 * Cc;
  f32x4 acc[4][4] = {};
  float4 av[4];
  // ---- prologue: A(0) regs + B(0) -> Bs[0] ----
#pragma unroll
  for (int i = 0; i < 4; ++i)
    av[i] = *(const float4*)&Xb[(size_t)(cg * 4 + i) * Nn];
#pragma unroll
  for (int j = 0; j < 2; ++j) {
    int li = tid + j * 256;
    int row = li >> 2;
    int kc = ((li & 3) ^ ((li >> 3) & 3)) * 8;
    async_ld16(Bbp + (size_t)row * Cc + kc, (char*)Bs + li * 16);
  }
  int cur = 0;
  for (int kt = 0; kt < 16; ++kt) {
    // ---- commit A(kt) to As[cur] (implicit wait on av only) ----
    unsigned short* Aw = As + cur * AE;
    int slot = cg ^ (ng & 7);
#pragma unroll
    for (int j = 0; j < 4; ++j) {
      int n = ng * 4 + j;
      ushort4 w;
      w.x = f2bf(av[0][j]);
      w.y = f2bf(av[1][j]);
      w.z = f2bf(av[2][j]);
      w.w = f2bf(av[3][j]);
      *(ushort4*)&Aw[n * LDA + slot * 4] = w;
    }
    __syncthreads();  // drains B(kt) (a full phase in flight) + A writes visible
    // ---- prefetch next tile (hidden under frag reads + MFMA) ----
    if (kt < 15) {
      char* Bwr = (char*)(Bs + (cur ^ 1) * BE);
#pragma unroll
      for (int j = 0; j < 2; ++j) {
        int li = tid + j * 256;
        int row = li >> 2;
        int kc = ((li & 3) ^ ((li >> 3) & 3)) * 8;
        async_ld16(Bbp + (size_t)row * Cc + (kt + 1) * 32 + kc, Bwr + li * 16);
      }
#pragma unroll
      for (int i = 0; i < 4; ++i)
        av[i] = *(const float4*)&Xb[(size_t)((kt + 1) * 32 + cg * 4 + i) * Nn];
    }
    // ---- fragment reads + MFMA ----
    const unsigned short* Ar = As + cur * AE;
    const __hip_bfloat16* Br = Bs + cur * BE;
    bf16x8 af[4], bfv[4];
#pragma unroll
    for (int m = 0; m < 4; ++m) {
      int row = wr + m * 16 + (lane & 15);
      int h = (row >> 2) & 7;
      int g = lane >> 4;
      int s0 = (2 * g) ^ h, s1 = (2 * g + 1) ^ h;
      union { ushort4 u2[2]; bf16x8 v8; } t;
      t.u2[0] = *(const ushort4*)&Ar[row * LDA + s0 * 4];
      t.u2[1] = *(const ushort4*)&Ar[row * LDA + s1 * 4];
      af[m] = t.v8;
    }
#pragma unroll
    for (int nf = 0; nf < 4; ++nf) {
      int row = wc + nf * 16 + (lane & 15);
      int q = (lane >> 4) ^ ((row >> 1) & 3);
      bfv[nf] = *(const bf16x8*)&Br[row * 32 + q * 8];
    }
#pragma unroll
    for (int m = 0; m < 4; ++m)
#pragma unroll
      for (int nf = 0; nf < 4; ++nf)
        acc[m][nf] = __builtin_amdgcn_mfma_f32_16x16x32_bf16(af[m], bfv[nf], acc[m][nf], 0, 0, 0);
    cur ^= 1;
  }
  __hip_bfloat16* Zb = Z + ((size_t)b * Nn + n0) * Cc + c0;
#pragma unroll
  for (int nf = 0; nf < 4; ++nf) {
    int col = wc + nf * 16 + (lane & 15);
    float bv = bias[c0 + col];
#pragma unroll
    for (int m = 0; m < 4; ++m) {
#pragma unroll
      for (int r = 0; r < 4; ++r) {
        int row = wr + m * 16 + (lane >> 4) * 4 + r;
        Zb[(size_t)row * Cc + col] = __float2bfloat16(acc[m][nf][r] + bv);
      }
    }
  }
}

// ---------------- K3: cross + softmax fused -> assign[b,n,k], asum[b,k] ----------------
// R7-measured version: single-buffer, 2 barriers/K-step, swizzled b128 frag reads.
__global__ __launch_bounds__(256) void k_cross(const __hip_bfloat16* __restrict__ Z,
                                               const __hip_bfloat16* __restrict__ CW,
                                               const float* __restrict__ scale,
                                               const float* __restrict__ cwsq,
                                               float* __restrict__ assign,
                                               float* __restrict__ asum) {
  __shared__ __align__(16) __hip_bfloat16 As[128 * 32];
  __shared__ __align__(16) __hip_bfloat16 Bs[32 * 32];
  __shared__ float s_zsq[128];
  __shared__ float s_asum[Kk];
  int b = blockIdx.y;
  int n0 = blockIdx.x * 128;
  int tid = threadIdx.x, lane = tid & 63, wid = tid >> 6;
  if (tid < Kk) s_asum[tid] = 0.f;
  const __hip_bfloat16* Ab = Z + ((size_t)b * Nn + n0) * Cc;
  f32x4 acc[2][2] = {};
  float sq = 0.f;
  for (int kt = 0; kt < 16; ++kt) {
    int k0 = kt * 32;
    __syncthreads();
#pragma unroll
    for (int j = 0; j < 2; ++j) {
      int li = tid + j * 256;
      int row = li >> 2;
      int kc = ((li & 3) ^ ((li >> 3) & 3)) * 8;
      async_ld16(Ab + (size_t)row * Cc + k0 + kc, (char*)As + li * 16);
    }
    if (tid < 128) {
      int row = tid >> 2;
      int kc = ((tid & 3) ^ ((tid >> 3) & 3)) * 8;
      async_ld16(CW + (size_t)row * Cc + k0 + kc, (char*)Bs + tid * 16);
    }
    __syncthreads();
    {  // z_sq partial: 2 swizzled b128 reads
      int row = tid >> 1, h = tid & 1;
      int rsw = (row >> 1) & 3;
#pragma unroll
      for (int c8 = 0; c8 < 2; ++c8) {
        union { bf16x8 v; __hip_bfloat16 e[8]; } t;
        t.v = *(const bf16x8*)&As[row * 32 + (((2 * h + c8) ^ rsw) * 8)];
#pragma unroll
        for (int i = 0; i < 8; ++i) {
          float v = __bfloat162float(t.e[i]);
          sq += v * v;
        }
      }
    }
    bf16x8 af[2], bfv[2];
#pragma unroll
    for (int m = 0; m < 2; ++m) {
      int row = wid * 32 + m * 16 + (lane & 15);
      int q = (lane >> 4) ^ ((row >> 1) & 3);
      af[m] = *(const bf16x8*)&As[row * 32 + q * 8];
    }
#pragma unroll
    for (int nf = 0; nf < 2; ++nf) {
      int row = nf * 16 + (lane & 15);
      int q = (lane >> 4) ^ ((row >> 1) & 3);
      bfv[nf] = *(const bf16x8*)&Bs[row * 32 + q * 8];
    }
#pragma unroll
    for (int m = 0; m < 2; ++m)
#pragma unroll
      for (int nf = 0; nf < 2; ++nf)
        acc[m][nf] = __builtin_amdgcn_mfma_f32_16x16x32_bf16(af[m], bfv[nf], acc[m][nf], 0, 0, 0);
  }
  sq += __shfl_xor(sq, 1);
  if ((tid & 1) == 0) s_zsq[tid >> 1] = sq;
  __syncthreads();
  // ---- in-register softmax over k ----
  float sc[2], cq[2];
#pragma unroll
  for (int nf = 0; nf < 2; ++nf) {
    sc[nf] = scale[nf * 16 + (lane & 15)];
    cq[nf] = cwsq[nf * 16 + (lane & 15)];
  }
  float asump0 = 0.f, asump1 = 0.f;
#pragma unroll
  for (int m = 0; m < 2; ++m) {
#pragma unroll
    for (int r = 0; r < 4; ++r) {
      int row = wid * 32 + m * 16 + (lane >> 4) * 4 + r;
      float zq = s_zsq[row];
      float v0 = sc[0] * (zq - 2.f * acc[m][0][r] + cq[0]);
      float v1 = sc[1] * (zq - 2.f * acc[m][1][r] + cq[1]);
      float mx = fmaxf(v0, v1);
#pragma unroll
      for (int off = 1; off < 16; off <<= 1) mx = fmaxf(mx, __shfl_xor(mx, off));
      float e0 = __expf(v0 - mx), e1 = __expf(v1 - mx);
      float s = e0 + e1;
#pragma unroll
      for (int off = 1; off < 16; off <<= 1) s += __shfl_xor(s, off);
      float inv = 1.f / s;
      float a0 = e0 * inv, a1 = e1 * inv;
      acc[m][0][r] = a0;
      acc[m][1][r] = a1;
      asump0 += a0;
      asump1 += a1;
    }
  }
  asump0 += __shfl_xor(asump0, 16); asump0 += __shfl_xor(asump0, 32);
  asump1 += __shfl_xor(asump1, 16); asump1 += __shfl_xor(asump1, 32);
  if (lane < 16) {
    atomicAdd(&s_asum[lane], asump0);
    atomicAdd(&s_asum[16 + lane], asump1);
  }
  float* Cb = assign + ((size_t)b * Nn + n0) * Kk;
#pragma unroll
  for (int m = 0; m < 2; ++m)
#pragma unroll
    for (int nf = 0; nf < 2; ++nf) {
      int col = nf * 16 + (lane & 15);
#pragma unroll
      for (int r = 0; r < 4; ++r) {
        int row = wid * 32 + m * 16 + (lane >> 4) * 4 + r;
        Cb[(size_t)row * Kk + col] = acc[m][nf][r];
      }
    }
  __syncthreads();
  if (tid < Kk) atomicAdd(&asum[b * Kk + tid], s_asum[tid]);
}

// ---------------- K5: enc partials: part[s][b][k][c]  (128-n chunks, R7 best) ----------------
__global__ __launch_bounds__(256) void k_enc_part(const float* __restrict__ assign,
                                                  const __hip_bfloat16* __restrict__ Z,
                                                  float* __restrict__ part) {
  __shared__ float sa[128][Kk];
  int b = blockIdx.z;
  int s = blockIdx.y;
  int c = blockIdx.x * 256 + threadIdx.x;
  int tid = threadIdx.x;
  int n0 = s * 128;
  const float* ap = assign + ((size_t)b * Nn + n0) * Kk;
  for (int i = tid; i < 128 * Kk; i += 256) sa[i >> 5][i & 31] = ap[i];
  __syncthreads();
  float acc[Kk];
#pragma unroll
  for (int k = 0; k < Kk; ++k) acc[k] = 0.f;
  const __hip_bfloat16* zp = Z + ((size_t)b * Nn + n0) * Cc + c;
  for (int n = 0; n < 128; ++n) {
    float zv = __bfloat162float(zp[(size_t)n * Cc]);
    const float4* sp = (const float4*)&sa[n][0];
#pragma unroll
    for (int q = 0; q < 8; ++q) {
      float4 a4 = sp[q];
      acc[4 * q + 0] = fmaf(a4.x, zv, acc[4 * q + 0]);
      acc[4 * q + 1] = fmaf(a4.y, zv, acc[4 * q + 1]);
      acc[4 * q + 2] = fmaf(a4.z, zv, acc[4 * q + 2]);
      acc[4 * q + 3] = fmaf(a4.w, zv, acc[4 * q + 3]);
    }
  }
  float* pp = part + (((size_t)s * Bb + b) * Kk) * Cc + c;
#pragma unroll
  for (int k = 0; k < Kk; ++k) pp[(size_t)k * Cc] = acc[k];
}

// ---------------- K6: reduce partials + BN + relu + mean-atomic -> ef ----------------
__global__ __launch_bounds__(256) void k_enc_bn(const float* __restrict__ part,
                                                const float* __restrict__ asum,
                                                const float* __restrict__ cw,
                                                const float* __restrict__ bn_g,
                                                const float* __restrict__ bn_b,
                                                const float* __restrict__ bn_m,
                                                const float* __restrict__ bn_v,
                                                float* __restrict__ ef) {
  int bk = blockIdx.x;  // b*32+k
  int b = bk >> 5, k = bk & 31;
  int tid = threadIdx.x;
  float g = bn_g[k], bt = bn_b[k], mn = bn_m[k], iv = rsqrtf(bn_v[k] + 1e-5f);
  float as = asum[bk];
  for (int c = tid; c < Cc; c += 256) {
    float e = 0.f;
#pragma unroll
    for (int s = 0; s < NSPLIT; ++s)
      e += part[(((size_t)s * Bb + b) * Kk + k) * Cc + c];
    e -= as * cw[k * Cc + c];
    e = (e - mn) * (iv * g) + bt;
    e = fmaxf(e, 0.f);
    atomicAdd(&ef[b * Cc + c], e * (1.f / 32.f));
  }
}

// ---------------- K8: fc + sigmoid -> gamma[b][o] ----------------
__global__ void k_fc(const float* __restrict__ ef, const float* __restrict__ fcw,
                     const float* __restrict__ fcb, float* __restrict__ gamma) {
  int b = blockIdx.x;
  int o = blockIdx.y * 4 + (threadIdx.x >> 6);
  int lane = threadIdx.x & 63;
  const float* w = fcw + (size_t)o * Cc;
  const float* e = ef + b * Cc;
  float s = 0.f;
#pragma unroll
  for (int j = 0; j < 8; ++j) s += e[lane + j * 64] * w[lane + j * 64];
  for (int off = 32; off; off >>= 1) s += __shfl_down(s, off);
  if (lane == 0) gamma[b * Cc + o] = 1.f / (1.f + __expf(-(s + fcb[o])));
}

// ---------------- K9: output = relu(x * (1+gamma)), one block per (b,c) ----------------
__global__ __launch_bounds__(256) void k_out(const float* __restrict__ x,
                                             const float* __restrict__ gamma,
                                             float* __restrict__ out) {
  int bc = blockIdx.x;
  float m = 1.f + gamma[bc];
  size_t base = (size_t)bc * (Nn / 4);
  const float4* xp = (const float4*)x + base;
  float4* op = (float4*)out + base;
#pragma unroll
  for (int j = 0; j < 4; ++j) {
    int i = j * 256 + threadIdx.x;
    float4 v = xp[i];
    float4 r;
    r.x = fmaxf(v.x * m, 0.f);
    r.y = fmaxf(v.y * m, 0.f);
    r.z = fmaxf(v.z * m, 0.f);
    r.w = fmaxf(v.w * m, 0.f);
    op[i] = r;
  }
}

extern "C" void kernel_launch(void* const* d_in, const int* in_sizes, int n_in,
                              void* d_out, int out_size, void* d_ws, size_t ws_size,
                              hipStream_t stream) {
  const float* x = (const float*)d_in[0];
  const float* conv_w = (const float*)d_in[1];
  const float* conv_b = (const float*)d_in[2];
  const float* codewords = (const float*)d_in[3];
  const float* scale = (const float*)d_in[4];
  const float* bn_gamma = (const float*)d_in[5];
  const float* bn_beta = (const float*)d_in[6];
  const float* bn_mean = (const float*)d_in[7];
  const float* bn_var = (const float*)d_in[8];
  const float* fc_w = (const float*)d_in[9];
  const float* fc_b = (const float*)d_in[10];

  float* ef_out = (float*)d_out;            // [16][512]
  float* out = (float*)d_out + Bb * Cc;     // [16][512][4096]

  char* ws = (char*)d_ws;
  size_t off = 0;
  float* part = (float*)(ws + off);                  // 32 MB
  off += (size_t)NSPLIT * Bb * Kk * Cc * 4;
  __hip_bfloat16* z = (__hip_bfloat16*)(ws + off);   // 64 MB
  off += (size_t)Bb * Nn * Cc * 2;
  float* assign = (float*)(ws + off);                // 8 MB
  off += (size_t)Bb * Nn * Kk * 4;
  __hip_bfloat16* wbf = (__hip_bfloat16*)(ws + off);
  off += (size_t)Cc * Cc * 2;
  __hip_bfloat16* cwb = (__hip_bfloat16*)(ws + off);
  off += (size_t)Kk * Cc * 2;
  float* cwsq = (float*)(ws + off);
  off += 512;
  float* asum = (float*)(ws + off);
  off += (size_t)Bb * Kk * 4;
  float* gamma = (float*)(ws + off);
  off += (size_t)Bb * Cc * 4;
  (void)ws_size; (void)n_in; (void)in_sizes; (void)out_size;

  hipMemsetAsync(asum, 0, Bb * Kk * 4, stream);
  hipMemsetAsync(ef_out, 0, Bb * Cc * 4, stream);  // mean accumulated via atomics

  k_prep<<<dim3(1024 + Kk / 4), dim3(256), 0, stream>>>(conv_w, wbf, codewords, cwb, cwsq);
  k_gemm_z<<<dim3((Nn / 128) * 4, Bb), dim3(256), 0, stream>>>(x, wbf, conv_b, z);
  k_cross<<<dim3(Nn / 128, Bb), dim3(256), 0, stream>>>(z, cwb, scale, cwsq, assign, asum);
  k_enc_part<<<dim3(Cc / 256, NSPLIT, Bb), dim3(256), 0, stream>>>(assign, z, part);
  k_enc_bn<<<dim3(Bb * Kk), dim3(256), 0, stream>>>(part, asum, codewords, bn_gamma, bn_beta,
                                                    bn_mean, bn_var, ef_out);
  k_fc<<<dim3(Bb, Cc / 4), dim3(256), 0, stream>>>(ef_out, fc_w, fc_b, gamma);
  k_out<<<dim3(Bb * Cc), dim3(256), 0, stream>>>(x, gamma, out);
}